// Round 6
// baseline (127.691 us; speedup 1.0000x reference)
//
#include <hip/hip_runtime.h>
#include <math.h>

#define NCLUS 56
#define HH 224
#define WW 224
#define BB 32
#define CELLS (NCLUS * NCLUS) /* 3136 */
#define HW (HH * WW)

typedef float f32x4 __attribute__((ext_vector_type(4)));

// ---------------------------------------------------------------------------
// Kernel A: Sobel -> grad mag -> inverted -> 4x4 mean pool. (unchanged)
// ---------------------------------------------------------------------------
__global__ __launch_bounds__(256) void pool_kernel(const float* __restrict__ cf,
                                                   float* __restrict__ pooled) {
    __shared__ float lds[18][226];
    int b = blockIdx.x / 14;
    int grp = blockIdx.x - b * 14;
    int tid = threadIdx.x;
    const float* e = cf + ((size_t)b * 65 + 64) * HW;

    int y0 = grp * 16 - 1;
    for (int t = tid; t < 18 * 224; t += 256) {
        int r = t / 224;
        int c = t - r * 224;
        int y = y0 + r;
        lds[r][c + 1] = (y >= 0 && y < HH) ? e[y * WW + c] : 0.0f;
    }
    if (tid < 18) { lds[tid][0] = 0.0f; lds[tid][225] = 0.0f; }
    __syncthreads();

    if (tid >= 224) return;
    int lby = tid / 56;
    int bx = tid - lby * 56;
    int r0 = lby * 4;
    int c0 = bx * 4;

    float patch[6][6];
#pragma unroll
    for (int i = 0; i < 6; ++i)
#pragma unroll
        for (int j = 0; j < 6; ++j) patch[i][j] = lds[r0 + i][c0 + j];

    float s = 0.0f;
#pragma unroll
    for (int iy = 0; iy < 4; ++iy) {
#pragma unroll
        for (int ix = 0; ix < 4; ++ix) {
            float gx = (patch[iy][ix + 2] - patch[iy][ix])
                     + 2.0f * (patch[iy + 1][ix + 2] - patch[iy + 1][ix])
                     + (patch[iy + 2][ix + 2] - patch[iy + 2][ix]);
            float gy = (patch[iy + 2][ix] - patch[iy][ix])
                     + 2.0f * (patch[iy + 2][ix + 1] - patch[iy][ix + 1])
                     + (patch[iy + 2][ix + 2] - patch[iy][ix + 2]);
            float gm = sqrtf(gx * gx + gy * gy);
            s += 1.0f - 0.5f * gm;
        }
    }
    pooled[b * CELLS + (grp * 4 + lby) * NCLUS + bx] = s * 0.0625f;
}

// ---------------------------------------------------------------------------
// Kernel B: per-batch top-56 via radix select + rank sort. (unchanged)
// ---------------------------------------------------------------------------
__global__ __launch_bounds__(256) void topk_kernel(
        const float* __restrict__ pooled,
        float* __restrict__ sy, float* __restrict__ sx) {
    int b = blockIdx.x;
    int tid = threadIdx.x;
    __shared__ unsigned long long list[CELLS];
    __shared__ unsigned nlist_s;
    if (tid == 0) nlist_s = 0;

    if (tid < 64) {
        unsigned hi[49];
#pragma unroll
        for (int j = 0; j < 49; ++j) {
            int i = j * 64 + tid;
            unsigned u = __float_as_uint(pooled[b * CELLS + i]);
            hi[j] = (u & 0x80000000u) ? ~u : (u | 0x80000000u);
        }
        unsigned prefix = 0;
        unsigned cnt = CELLS;
        for (int bit = 31; bit >= 0; --bit) {
            if (cnt <= 448u) break;
            unsigned cand = prefix | (1u << bit);
            unsigned c = 0;
#pragma unroll
            for (int j = 0; j < 49; ++j) c += (hi[j] >= cand) ? 1u : 0u;
#pragma unroll
            for (int off = 32; off >= 1; off >>= 1)
                c += __shfl_xor(c, off, 64);
            if (c >= (unsigned)NCLUS) { prefix = cand; cnt = c; } // uniform
        }
#pragma unroll
        for (int j = 0; j < 49; ++j) {
            if (hi[j] >= prefix) {
                unsigned pos = atomicAdd(&nlist_s, 1u);
                unsigned i = (unsigned)(j * 64 + tid);
                list[pos] = ((unsigned long long)hi[j] << 32) |
                            (unsigned long long)(0xFFFFFFFFu - i);
            }
        }
    }
    __syncthreads();

    int N = (int)nlist_s;
    for (int c = tid; c < N; c += 256) {
        unsigned long long key = list[c];
        int r = 0;
        for (int j = 0; j < N; ++j) r += (list[j] > key) ? 1 : 0;
        if (r < NCLUS) {
            unsigned idx = 0xFFFFFFFFu - (unsigned)(key & 0xFFFFFFFFull);
            sy[b * NCLUS + r] = (float)(idx / NCLUS) / (float)NCLUS;
            sx[b * NCLUS + r] = (float)(idx % NCLUS) / (float)NCLUS;
        }
    }
}

// ---------------------------------------------------------------------------
// Kernel C1: softmax denominators. Round-4 markers structure (fp32 LDS fx
// table, fused gen) with the 56-plane store loop replaced by one float4
// store of Sinv = 1/sum per (h, 4w). Writes only 6.4MB.
// ---------------------------------------------------------------------------
__global__ __launch_bounds__(448) void sums_kernel(
        const float* __restrict__ sy, const float* __restrict__ sx,
        const float* __restrict__ stdp, float* __restrict__ Sinv) {
    __shared__ float fx_lds[NCLUS][WW]; // 50,176 B
    __shared__ float fy_s[8 * NCLUS];   //  1,792 B
    int blk = blockIdx.x;
    int b = blk / 28;
    int h0 = (blk - b * 28) * 8;
    int tid = threadIdx.x;
    float inv_std = 1.0f / stdp[0];
    const float* syb = sy + b * NCLUS;
    const float* sxb = sx + b * NCLUS;

    for (int t = tid; t < NCLUS * WW; t += 448) {
        int k = t / WW;
        int w = t - k * WW;
        float tx = ((float)w / 224.0f - sxb[k]) * inv_std;
        fx_lds[k][w] = expf(0.5f * expf(-(tx * tx)));
    }
    {
        int row = tid / NCLUS;
        int k = tid - row * NCLUS;
        float ty = ((float)(h0 + row) / 224.0f - syb[k]) * inv_std;
        fy_s[tid] = expf(0.5f * expf(-(ty * ty)));
    }
    __syncthreads();

    int row = tid / 56;      // 0..7
    int wq = tid - row * 56; // 0..55 -> w = 4*wq
    const float* fyp = fy_s + row * NCLUS;

    float s0 = 0.f, s1 = 0.f, s2 = 0.f, s3 = 0.f;
#pragma unroll 8
    for (int k = 0; k < NCLUS; ++k) {
        float fy = fyp[k];
        f32x4 fx = *(const f32x4*)&fx_lds[k][wq * 4];
        s0 = fmaf(fy, fx.x, s0);
        s1 = fmaf(fy, fx.y, s1);
        s2 = fmaf(fy, fx.z, s2);
        s3 = fmaf(fy, fx.w, s3);
    }
    f32x4 r;
    r.x = 1.0f / s0;
    r.y = 1.0f / s1;
    r.z = 1.0f / s2;
    r.w = 1.0f / s3;
    *(f32x4*)(Sinv + (size_t)b * HW + (size_t)(h0 + row) * WW + wq * 4) = r;
}

// ---------------------------------------------------------------------------
// Kernel C2: scale + store, SEQUENTIAL writes. One block per (b,k) plane
// (1792 blocks = 7/CU exactly). Block regenerates its own fy/fx tables
// (448 exps) into LDS, then streams the 200KB plane: one contiguous float4
// read of Sinv (LLC-resident, 6.4MB total) and one contiguous float4 write
// of out per element-quad. This is the DRAM-locality hypothesis test: the
// write stream is now fill-kernel-shaped.
// ---------------------------------------------------------------------------
__global__ __launch_bounds__(256) void scale_kernel(
        const float* __restrict__ sy, const float* __restrict__ sx,
        const float* __restrict__ stdp, const float* __restrict__ Sinv,
        float* __restrict__ out) {
    __shared__ float fy_l[HH];
    __shared__ float fx_l[WW];
    int blk = blockIdx.x; // b*56 + k
    int b = blk / NCLUS;
    int k = blk - b * NCLUS;
    int tid = threadIdx.x;
    float inv_std = 1.0f / stdp[0];
    float syk = sy[b * NCLUS + k];
    float sxk = sx[b * NCLUS + k];

    for (int t = tid; t < HH; t += 256) {
        float c = (float)t / 224.0f;
        float ty = (c - syk) * inv_std;
        float tx = (c - sxk) * inv_std;
        fy_l[t] = expf(0.5f * expf(-(ty * ty)));
        fx_l[t] = expf(0.5f * expf(-(tx * tx)));
    }
    __syncthreads();

    const f32x4* sp = (const f32x4*)(Sinv + (size_t)b * HW);
    f32x4* op = (f32x4*)(out + ((size_t)b * NCLUS + k) * HW);
#pragma unroll 7
    for (int i = 0; i < 49; ++i) {
        int e = i * 256 + tid;       // quad index within plane, 0..12543
        int h = e / 56;              // 224/4 = 56 quads per row
        int w4 = e - h * 56;
        f32x4 sv = sp[e];
        float fy = fy_l[h];
        f32x4 fx = *(const f32x4*)&fx_l[w4 * 4];
        f32x4 o;
        o.x = fy * fx.x * sv.x;
        o.y = fy * fx.y * sv.y;
        o.z = fy * fx.z * sv.z;
        o.w = fy * fx.w * sv.w;
        op[e] = o;
    }
}

// ---------------------------------------------------------------------------
extern "C" void kernel_launch(void* const* d_in, const int* in_sizes, int n_in,
                              void* d_out, int out_size, void* d_ws,
                              size_t ws_size, hipStream_t stream) {
    const float* cf = (const float*)d_in[0];   // (32, 65, 224, 224) f32
    const float* stdp = (const float*)d_in[1]; // scalar f32
    float* out = (float*)d_out;                // (32, 56, 224, 224) f32

    char* ws = (char*)d_ws;
    float* pooled = (float*)ws;                 // 401 KB
    float* sy = (float*)(ws + 512 * 1024);      // 7 KB
    float* sx = (float*)(ws + 576 * 1024);      // 7 KB
    float* Sinv = (float*)(ws + 1024 * 1024);   // 6.42 MB

    pool_kernel<<<BB * 14, 256, 0, stream>>>(cf, pooled);
    topk_kernel<<<BB, 256, 0, stream>>>(pooled, sy, sx);
    sums_kernel<<<BB * 28, 448, 0, stream>>>(sy, sx, stdp, Sinv);
    scale_kernel<<<BB * NCLUS, 256, 0, stream>>>(sy, sx, stdp, Sinv, out);
}